// Round 10
// baseline (267.491 us; speedup 1.0000x reference)
//
#include <hip/hip_runtime.h>

#define L_SEQ 2048
#define BATCH 2
#define CDIM  1024
#define NH    16
#define HD    64

typedef __attribute__((ext_vector_type(8))) short short8;
typedef __attribute__((ext_vector_type(4))) float floatx4;

// 0.125 * log2(e): folds hd^-0.5 and the exp->exp2 conversion into Q/rel scaling
#define QSCALE 0.18033688011112042f

__device__ __forceinline__ unsigned short f2bf(float f){
  unsigned int u = __builtin_bit_cast(unsigned int, f);
  u += 0x7fffu + ((u >> 16) & 1u);
  return (unsigned short)(u >> 16);
}

// packed f32x2 -> bf16x2, single HW instruction (NOT RNE -> only where 1ulp ok)
__device__ __forceinline__ unsigned cvtpk(float lo, float hi){
  unsigned r;
  asm("v_cvt_pk_bf16_f32 %0, %1, %2" : "=v"(r) : "v"(lo), "v"(hi));
  return r;
}

__device__ __forceinline__ void gload_lds16(const void* g, void* l){
  typedef __attribute__((address_space(1))) void gv_t;
  typedef __attribute__((address_space(3))) void sv_t;
  __builtin_amdgcn_global_load_lds((gv_t*)(void*)g, (sv_t*)l, 16, 0, 0);
}

// ---------------- prep_x: (L,B,C) f32 -> (B*L, C) bf16 ----------------
__global__ void __launch_bounds__(256) prep_x(const float* __restrict__ x,
                                              unsigned short* __restrict__ xb){
  int idx = blockIdx.x * 256 + threadIdx.x;     // over L*B*C/4 = 1048576
  int c4 = idx & 255;                           // C/4 = 256
  int lb = idx >> 8;                            // l*B + b
  int b  = lb & (BATCH - 1);
  int l  = lb >> 1;
  float4 v = ((const float4*)x)[idx];
  ushort4 s;
  s.x = f2bf(v.x); s.y = f2bf(v.y); s.z = f2bf(v.z); s.w = f2bf(v.w);
  *(ushort4*)&xb[(size_t)(b*L_SEQ + l)*CDIM + c4*4] = s;
}

// ---------------- prep_w: transpose f32 (K,N) -> bf16 (N,K) ----------------
__global__ void __launch_bounds__(256) prep_w(const float* __restrict__ Wq,
    const float* __restrict__ Wk, const float* __restrict__ Wv,
    const float* __restrict__ Wo, unsigned short* __restrict__ Wqkvt,
    unsigned short* __restrict__ Wot){
  __shared__ float tile[32][33];
  int z = blockIdx.z;
  const float* W = (z==0)?Wq:(z==1)?Wk:(z==2)?Wv:Wo;
  unsigned short* dst = (z==3) ? Wot : (Wqkvt + (size_t)z*CDIM*CDIM);
  int tx = threadIdx.x & 31, ty = threadIdx.x >> 5;   // 32 x 8
  int X = blockIdx.x*32, Y = blockIdx.y*32;
  #pragma unroll
  for (int i=0;i<4;i++)
    tile[ty + i*8][tx] = W[(size_t)(Y + ty + i*8)*CDIM + X + tx];
  __syncthreads();
  #pragma unroll
  for (int i=0;i<4;i++)
    dst[(size_t)(X + ty + i*8)*CDIM + Y + tx] = f2bf(tile[tx][ty + i*8]);
}

// ---------------- gemm_bt: C = A(MxK) * Bt(NxK)^T, bf16 MFMA ----------------
// MODE 0: QKV epilogue (bias, scatter; Q pre-scaled by 0.125*log2e).
//         V-section blocks (rowB0>=2048) bounce C through LDS for coalesced V^T writes.
// MODE 1: out epilogue (bias bo, fp32 (L,B,C))
template<int MODE>
__global__ void __launch_bounds__(256) gemm_bt(
    const unsigned short* __restrict__ A,
    const unsigned short* __restrict__ Bt,
    int Kdim,
    const float* __restrict__ b0, const float* __restrict__ b1,
    const float* __restrict__ b2,
    unsigned short* __restrict__ qo, unsigned short* __restrict__ ko,
    unsigned short* __restrict__ vo, float* __restrict__ out)
{
  constexpr int SMEM_HW = (MODE==0) ? 16640 : 8192;   // halfwords (V-bounce 128*130)
  __shared__ __align__(16) unsigned short smem[SMEM_HW];
  unsigned short* Asm = &smem[0];
  unsigned short* Bsm = &smem[4096];
  unsigned short* Vb  = &smem[0];        // V-bounce, reuses Asm/Bsm after K-loop
  const int t    = threadIdx.x;
  const int lane = t & 63;
  const int wave = t >> 6;
  const int wr = wave >> 1, wc = wave & 1;
  const int g = lane >> 4, lr = lane & 15;
  const int rowA0 = blockIdx.x * 128;
  const int rowB0 = blockIdx.y * 128;

  floatx4 acc[4][4] = {};

  const int r_st = t >> 2;          // staging row 0..63
  const int k_st = (t & 3) * 8;     // staging k offset

  for (int k0 = 0; k0 < Kdim; k0 += 32) {
    const unsigned short* ga = A  + (size_t)(rowA0 + r_st) * Kdim + k0 + k_st;
    const unsigned short* gb = Bt + (size_t)(rowB0 + r_st) * Kdim + k0 + k_st;
    gload_lds16(ga,                   &Asm[t*8]);
    gload_lds16(ga + (size_t)64*Kdim, &Asm[2048 + t*8]);
    gload_lds16(gb,                   &Bsm[t*8]);
    gload_lds16(gb + (size_t)64*Kdim, &Bsm[2048 + t*8]);
    __syncthreads();
    short8 af[4], bfr[4];
    #pragma unroll
    for (int mi=0;mi<4;mi++)
      af[mi] = *(const short8*)&Asm[(wr*64 + mi*16 + lr)*32 + g*8];
    #pragma unroll
    for (int ni=0;ni<4;ni++)
      bfr[ni] = *(const short8*)&Bsm[(wc*64 + ni*16 + lr)*32 + g*8];
    #pragma unroll
    for (int mi=0;mi<4;mi++)
      #pragma unroll
      for (int ni=0;ni<4;ni++)
        acc[mi][ni] = __builtin_amdgcn_mfma_f32_16x16x32_bf16(af[mi], bfr[ni], acc[mi][ni], 0, 0, 0);
    __syncthreads();
  }

  if (MODE==0 && rowB0 >= 2048) {
    // ---- V-section: LDS bounce (stride 130 hw = 65 dwords -> full bank spread),
    //      then coalesced V^T write (each thread 128B contiguous). RNE rounding. ----
    #pragma unroll
    for (int mi=0;mi<4;mi++){
      const int rloc = wr*64 + mi*16 + g*4;
      #pragma unroll
      for (int ni=0;ni<4;ni++){
        const int cloc = wc*64 + ni*16 + lr;
        const float bias = b2[(rowB0 + cloc) & 1023];
        ushort4 s;
        s.x = f2bf(acc[mi][ni][0]+bias); s.y = f2bf(acc[mi][ni][1]+bias);
        s.z = f2bf(acc[mi][ni][2]+bias); s.w = f2bf(acc[mi][ni][3]+bias);
        *(ushort4*)&Vb[cloc*130 + rloc] = s;
      }
    }
    __syncthreads();
    const int dloc = t >> 1, half = t & 1;
    const int nl = (rowB0 + dloc) & 1023;
    const int h = nl >> 6, d = nl & 63;
    const int b = rowA0 >> 11;
    const int l0 = (rowA0 & 2047) + half*64;
    unsigned short* dst = &vo[((size_t)((b*NH + h)*HD + d))*L_SEQ + l0];
    const unsigned short* srcp = &Vb[dloc*130 + half*64];
    #pragma unroll
    for (int i=0;i<8;i++)
      *(short8*)&dst[i*8] = *(const short8*)&srcp[i*8];
    return;
  }

  #pragma unroll
  for (int mi=0;mi<4;mi++){
    const int rb = rowA0 + wr*64 + mi*16 + g*4;
    #pragma unroll
    for (int ni=0;ni<4;ni++){
      const int col = rowB0 + wc*64 + ni*16 + lr;
      if (MODE == 0) {
        const int sec = col >> 10;       // 0=Q, 1=K here (V handled above)
        const int nl  = col & 1023;
        const int h = nl >> 6, d = nl & 63;
        const float bias = (sec==0) ? b0[nl] : b1[nl];
        #pragma unroll
        for (int r=0;r<4;r++){
          const int row = rb + r;
          const int b = row >> 11, l = row & 2047;
          float v = acc[mi][ni][r] + bias;
          if (sec == 0) v *= QSCALE;             // fold hd^-0.5 * log2e into Q
          const unsigned short hv = f2bf(v);
          const size_t bh = (size_t)(b*NH + h);
          if (sec == 0) qo[(bh*L_SEQ + l)*HD + d] = hv;
          else          ko[(bh*L_SEQ + l)*HD + d] = hv;
        }
      } else {
        const float bias = b0[col];
        #pragma unroll
        for (int r=0;r<4;r++){
          const int row = rb + r;
          const int b = row >> 11, l = row & 2047;
          out[((size_t)l*BATCH + b)*CDIM + col] = acc[mi][ni][r] + bias;
        }
      }
    }
  }
}

// ---------------- flash attention: LDS-staged K/V, counted-vmcnt pipeline ----------------
// grid: x = b*NH+h (32), y = q-block (16) + qbase. Split into 2 dispatches so the
// other kernels surface in rocprof's top-5 (diagnostic).
__global__ void __launch_bounds__(256) attn_kernel(
    const unsigned short* __restrict__ Qb, const unsigned short* __restrict__ Kb,
    const unsigned short* __restrict__ Vt, const float* __restrict__ rel,
    unsigned short* __restrict__ Ab, int qbase)
{
  __shared__ unsigned short Ks[2][64*64];
  __shared__ unsigned short Vs[2][64*64];
  __shared__ unsigned int Pl[4*16*32];   // per-wave [16 q][32 u32], XOR-swizzled
  const int bh = blockIdx.x;
  const int qb = blockIdx.y + qbase;
  const int t = threadIdx.x, lane = t & 63, wave = t >> 6;
  const int g = lane >> 4, lr = lane & 15;

  const unsigned short* Qp = Qb + (size_t)bh * (L_SEQ*HD);
  const unsigned short* Kp = Kb + (size_t)bh * (L_SEQ*HD);
  const unsigned short* Vp = Vt + (size_t)bh * (HD*L_SEQ);

  const int q0 = qb*64 + wave*16;                 // this wave's q-rows
  const short8 qf0 = *(const short8*)&Qp[(size_t)(q0 + lr)*HD + g*8];
  const short8 qf1 = *(const short8*)&Qp[(size_t)(q0 + lr)*HD + 32 + g*8];

  // rel index for key k: k - q + 2047; per-lane base
  const float* relp = rel + (2047 - q0 - lr + g*4);

  unsigned int* pw = Pl + wave*512 + lr*32;
  const int swz = lr & 7;

  // all-ones bf16 A-fragment for MFMA row-sum (layout-independent)
  const short ONE = (short)0x3F80;
  const short8 ones = { ONE,ONE,ONE,ONE,ONE,ONE,ONE,ONE };

  // staging mapping: thread t covers LDS bytes [t*16, t*16+16) (+4096 on round 2)
  const int srow = t >> 3;                 // 0..31 (round adds 32; (row+32)&7==row&7)
  const int sxor = (t & 7) ^ (srow & 7);   // pre-swizzled source unit

  const unsigned short* kg = Kp + (size_t)srow*HD + sxor*8;
  const unsigned short* vg = Vp + (size_t)srow*L_SEQ + sxor*8;

  floatx4 o[4] = {};
  floatx4 osum = {};     // MFMA-accumulated row sums (all 4 entries equal)
  float m = -1e30f;

  // prologue: stage tile 0 into buffer 0 (completion enforced in-loop)
  gload_lds16(kg,           &Ks[0][t*8]);
  gload_lds16(kg + 32*HD,   &Ks[0][2048 + t*8]);
  gload_lds16(vg,           &Vs[0][t*8]);
  gload_lds16(vg + (size_t)32*L_SEQ, &Vs[0][2048 + t*8]);

  int cur = 0;
  for (int kb = 0; kb < L_SEQ; kb += 64) {
    // stage next tile (wraps to 0 on last iter; harmless)
    {
      const int kbn = (kb + 64) & (L_SEQ - 1);
      const unsigned short* kgn = kg + (size_t)kbn*HD;   // rows kbn+srow
      const unsigned short* vgn = vg + kbn;              // cols kbn
      unsigned short* kd = &Ks[cur^1][0];
      unsigned short* vd = &Vs[cur^1][0];
      gload_lds16(kgn,                    kd + t*8);
      gload_lds16(kgn + 32*HD,            kd + 2048 + t*8);
      gload_lds16(vgn,                    vd + t*8);
      gload_lds16(vgn + (size_t)32*L_SEQ, vd + 2048 + t*8);
    }
    // counted wait: 4 newest outstanding = stage(t+1); everything older (stage(t)) done
    asm volatile("s_waitcnt vmcnt(4)" ::: "memory");
    __builtin_amdgcn_s_barrier();

    // rel loads (global, L1/L2-resident)
    float relv[16];
    #pragma unroll
    for (int j=0;j<4;j++)
      #pragma unroll
      for (int r=0;r<4;r++)
        relv[4*j+r] = relp[kb + 16*j + r];

    // QK^T from LDS: lane holds 16 keys {16j+4g+r} for q-row q0+lr
    const unsigned short* kbuf = &Ks[cur][0];
    floatx4 s[4];
    #pragma unroll
    for (int j=0;j<4;j++){
      const int row = j*16 + lr;
      const short8 k0 = *(const short8*)&kbuf[row*64 + ((g    ) ^ swz)*8];
      const short8 k1 = *(const short8*)&kbuf[row*64 + ((4 + g) ^ swz)*8];
      floatx4 z = {};
      z = __builtin_amdgcn_mfma_f32_16x16x32_bf16(k0, qf0, z, 0,0,0);
      z = __builtin_amdgcn_mfma_f32_16x16x32_bf16(k1, qf1, z, 0,0,0);
      s[j] = z;
    }

    float p[16];
    #pragma unroll
    for (int j=0;j<4;j++)
      #pragma unroll
      for (int r=0;r<4;r++)
        p[4*j+r] = fmaf(relv[4*j+r], QSCALE, s[j][r]);   // log2-domain score

    // per-lane tile max: 3-input groups to fuse into v_max3_f32
    float ma = fmaxf(fmaxf(fmaxf(p[0],p[1]),p[2]),  fmaxf(fmaxf(p[3],p[4]),p[5]));
    float mb = fmaxf(fmaxf(fmaxf(p[6],p[7]),p[8]),  fmaxf(fmaxf(p[9],p[10]),p[11]));
    float mc = fmaxf(fmaxf(fmaxf(p[12],p[13]),p[14]), p[15]);
    float mxl = fmaxf(fmaxf(ma, mb), mc);

    // T13 defer-max: rescale only when max grew by >8 (exp2(8)=256 headroom)
    if (!__all(mxl <= m + 8.f)) {
      float mx = fmaxf(mxl, __shfl_xor(mxl, 16, 64));
      mx = fmaxf(mx, __shfl_xor(mx, 32, 64));
      const float mn = fmaxf(m, mx);
      const float al = exp2f(m - mn);
      m = mn;
      #pragma unroll
      for (int r=0;r<4;r++) osum[r] *= al;
      #pragma unroll
      for (int fb=0;fb<4;fb++)
        #pragma unroll
        for (int r=0;r<4;r++) o[fb][r] *= al;
    }

    #pragma unroll
    for (int i=0;i<16;i++) p[i] = exp2f(p[i] - m);

    // P -> LDS (per-wave): 128B rows, 16B-unit swizzle; cvt_pk packs
    #pragma unroll
    for (int j=0;j<4;j++){
      unsigned lo = cvtpk(p[4*j],   p[4*j+1]);
      unsigned hi = cvtpk(p[4*j+2], p[4*j+3]);
      const int unit = (2*j + (g>>1)) ^ swz;
      *(uint2*)&pw[unit*4 + (g&1)*2] = make_uint2(lo, hi);
    }
    asm volatile("" ::: "memory");
    const short8 pf0 = *(const short8*)&pw[((    g) ^ swz)*4];
    const short8 pf1 = *(const short8*)&pw[((4 + g) ^ swz)*4];
    asm volatile("" ::: "memory");

    // row-sum on the MFMA pipe: D[i][q] = sum_k P[q,k] for every i
    osum = __builtin_amdgcn_mfma_f32_16x16x32_bf16(ones, pf0, osum, 0,0,0);
    osum = __builtin_amdgcn_mfma_f32_16x16x32_bf16(ones, pf1, osum, 0,0,0);

    // PV from LDS V^T tile
    const unsigned short* vbuf = &Vs[cur][0];
    #pragma unroll
    for (int fb=0; fb<4; fb++){
      const int row = fb*16 + lr;
      const short8 v0 = *(const short8*)&vbuf[row*64 + ((g    ) ^ swz)*8];
      const short8 v1 = *(const short8*)&vbuf[row*64 + ((4 + g) ^ swz)*8];
      o[fb] = __builtin_amdgcn_mfma_f32_16x16x32_bf16(v0, pf0, o[fb], 0,0,0);
      o[fb] = __builtin_amdgcn_mfma_f32_16x16x32_bf16(v1, pf1, o[fb], 0,0,0);
    }

    // all reads of buf[cur] consumed (compiler lgkm-waits before MFMA use);
    // barrier before next iter's stage overwrites it
    __builtin_amdgcn_s_barrier();
    cur ^= 1;
  }

  // lane (g,lr) holds attn[q=q0+lr][d = fb*16 + g*4 + r]
  const float inv = 1.f / osum[0];
  const int b = bh >> 4, h = bh & 15;
  unsigned short* outp = &Ab[((size_t)(b*L_SEQ + q0 + lr))*CDIM + h*HD];
  #pragma unroll
  for (int fb=0; fb<4; fb++){
    #pragma unroll
    for (int rp=0; rp<2; rp++){
      *(unsigned int*)&outp[fb*16 + g*4 + 2*rp] =
          cvtpk(o[fb][2*rp] * inv, o[fb][2*rp+1] * inv);
    }
  }
}

extern "C" void kernel_launch(void* const* d_in, const int* in_sizes, int n_in,
                              void* d_out, int out_size, void* d_ws, size_t ws_size,
                              hipStream_t stream) {
  const float* x   = (const float*)d_in[0];
  const float* Wq  = (const float*)d_in[1];
  const float* bq  = (const float*)d_in[2];
  const float* Wk  = (const float*)d_in[3];
  const float* bk  = (const float*)d_in[4];
  const float* Wv  = (const float*)d_in[5];
  const float* bv  = (const float*)d_in[6];
  const float* Wo  = (const float*)d_in[7];
  const float* bo  = (const float*)d_in[8];
  const float* rel = (const float*)d_in[9];
  float* out = (float*)d_out;

  char* ws = (char*)d_ws;
  unsigned short* Xb    = (unsigned short*)(ws);                    // 8 MB (aliased with Ab)
  unsigned short* Wqkvt = (unsigned short*)(ws + (8u  << 20));      // 6 MB
  unsigned short* Wot   = (unsigned short*)(ws + (14u << 20));      // 2 MB
  unsigned short* Qb    = (unsigned short*)(ws + (16u << 20));      // 8 MB
  unsigned short* Kb    = (unsigned short*)(ws + (24u << 20));      // 8 MB
  unsigned short* Vt    = (unsigned short*)(ws + (32u << 20));      // 8 MB
  unsigned short* Ab    = Xb;  // Xb dead after QKV GEMM

  prep_x<<<4096, 256, 0, stream>>>(x, Xb);
  prep_w<<<dim3(32,32,4), 256, 0, stream>>>(Wq, Wk, Wv, Wo, Wqkvt, Wot);
  gemm_bt<0><<<dim3(32,24), 256, 0, stream>>>(Xb, Wqkvt, CDIM, bq, bk, bv,
                                              Qb, Kb, Vt, nullptr);
  attn_kernel<<<dim3(32,16), 256, 0, stream>>>(Qb, Kb, Vt, rel, Ab, 0);
  attn_kernel<<<dim3(32,16), 256, 0, stream>>>(Qb, Kb, Vt, rel, Ab, 16);
  gemm_bt<1><<<dim3(32,8), 256, 0, stream>>>(Ab, Wot, CDIM, bo, nullptr, nullptr,
                                             nullptr, nullptr, nullptr, out);
}

// Round 11
// 229.785 us; speedup vs baseline: 1.1641x; 1.1641x over previous
//
#include <hip/hip_runtime.h>

#define L_SEQ 2048
#define BATCH 2
#define CDIM  1024
#define NH    16
#define HD    64

typedef __attribute__((ext_vector_type(8))) short short8;
typedef __attribute__((ext_vector_type(4))) float floatx4;

// 0.125 * log2(e): folds hd^-0.5 and the exp->exp2 conversion into Q/rel scaling
#define QSCALE 0.18033688011112042f

__device__ __forceinline__ unsigned short f2bf(float f){
  unsigned int u = __builtin_bit_cast(unsigned int, f);
  u += 0x7fffu + ((u >> 16) & 1u);
  return (unsigned short)(u >> 16);
}

// packed f32x2 -> bf16x2, single HW instruction (NOT RNE -> only where 1ulp ok)
__device__ __forceinline__ unsigned cvtpk(float lo, float hi){
  unsigned r;
  asm("v_cvt_pk_bf16_f32 %0, %1, %2" : "=v"(r) : "v"(lo), "v"(hi));
  return r;
}

__device__ __forceinline__ void gload_lds16(const void* g, void* l){
  typedef __attribute__((address_space(1))) void gv_t;
  typedef __attribute__((address_space(3))) void sv_t;
  __builtin_amdgcn_global_load_lds((gv_t*)(void*)g, (sv_t*)l, 16, 0, 0);
}

// ---------------- prep_x: (L,B,C) f32 -> (B*L, C) bf16 ----------------
__global__ void __launch_bounds__(256) prep_x(const float* __restrict__ x,
                                              unsigned short* __restrict__ xb){
  int idx = blockIdx.x * 256 + threadIdx.x;     // over L*B*C/4 = 1048576
  int c4 = idx & 255;                           // C/4 = 256
  int lb = idx >> 8;                            // l*B + b
  int b  = lb & (BATCH - 1);
  int l  = lb >> 1;
  float4 v = ((const float4*)x)[idx];
  ushort4 s;
  s.x = f2bf(v.x); s.y = f2bf(v.y); s.z = f2bf(v.z); s.w = f2bf(v.w);
  *(ushort4*)&xb[(size_t)(b*L_SEQ + l)*CDIM + c4*4] = s;
}

// ---------------- prep_w: transpose f32 (K,N) -> bf16 (N,K) ----------------
__global__ void __launch_bounds__(256) prep_w(const float* __restrict__ Wq,
    const float* __restrict__ Wk, const float* __restrict__ Wv,
    const float* __restrict__ Wo, unsigned short* __restrict__ Wqkvt,
    unsigned short* __restrict__ Wot){
  __shared__ float tile[32][33];
  int z = blockIdx.z;
  const float* W = (z==0)?Wq:(z==1)?Wk:(z==2)?Wv:Wo;
  unsigned short* dst = (z==3) ? Wot : (Wqkvt + (size_t)z*CDIM*CDIM);
  int tx = threadIdx.x & 31, ty = threadIdx.x >> 5;   // 32 x 8
  int X = blockIdx.x*32, Y = blockIdx.y*32;
  #pragma unroll
  for (int i=0;i<4;i++)
    tile[ty + i*8][tx] = W[(size_t)(Y + ty + i*8)*CDIM + X + tx];
  __syncthreads();
  #pragma unroll
  for (int i=0;i<4;i++)
    dst[(size_t)(X + ty + i*8)*CDIM + Y + tx] = f2bf(tile[tx][ty + i*8]);
}

// ---------------- gemm_bt: C = A(MxK) * Bt(NxK)^T, bf16 MFMA ----------------
// Double-buffered LDS + counted vmcnt: stage(t+1) issued BEFORE compute(t),
// s_waitcnt vmcnt(4) waits only stage(t) (the attn-r5 pattern).
// MODE 0: QKV epilogue (bias, scatter; Q pre-scaled by 0.125*log2e; V^T packed 8B stores)
// MODE 1: out epilogue (bias bo, fp32 (L,B,C))
template<int MODE>
__global__ void __launch_bounds__(256) gemm_bt(
    const unsigned short* __restrict__ A,
    const unsigned short* __restrict__ Bt,
    int Kdim,
    const float* __restrict__ b0, const float* __restrict__ b1,
    const float* __restrict__ b2,
    unsigned short* __restrict__ qo, unsigned short* __restrict__ ko,
    unsigned short* __restrict__ vo, float* __restrict__ out)
{
  __shared__ __align__(16) unsigned short smem[16384];   // 2 x (A 4096 + B 4096) hw
  const int t    = threadIdx.x;
  const int lane = t & 63;
  const int wave = t >> 6;
  const int wr = wave >> 1, wc = wave & 1;
  const int g = lane >> 4, lr = lane & 15;
  const int rowA0 = blockIdx.x * 128;
  const int rowB0 = blockIdx.y * 128;

  floatx4 acc[4][4] = {};

  const int r_st = t >> 2;          // staging row 0..63
  const int k_st = (t & 3) * 8;     // staging k offset

  const unsigned short* ga0 = A  + (size_t)(rowA0 + r_st) * Kdim + k_st;
  const unsigned short* gb0 = Bt + (size_t)(rowB0 + r_st) * Kdim + k_st;

  // prologue: stage tile 0 into buffer 0
  gload_lds16(ga0,                   &smem[t*8]);
  gload_lds16(ga0 + (size_t)64*Kdim, &smem[2048 + t*8]);
  gload_lds16(gb0,                   &smem[4096 + t*8]);
  gload_lds16(gb0 + (size_t)64*Kdim, &smem[4096 + 2048 + t*8]);

  int cur = 0;
  for (int k0 = 0; k0 < Kdim; k0 += 32) {
    // stage next K-tile into the other buffer (wraps on last iter; harmless)
    {
      const int k1 = (k0 + 32) & (Kdim - 1);
      unsigned short* nb = &smem[(cur^1)*8192];
      gload_lds16(ga0 + k1,                   nb + t*8);
      gload_lds16(ga0 + k1 + (size_t)64*Kdim, nb + 2048 + t*8);
      gload_lds16(gb0 + k1,                   nb + 4096 + t*8);
      gload_lds16(gb0 + k1 + (size_t)64*Kdim, nb + 4096 + 2048 + t*8);
    }
    // wait only for stage(t) (4 newest outstanding = stage(t+1))
    asm volatile("s_waitcnt vmcnt(4)" ::: "memory");
    __builtin_amdgcn_s_barrier();

    const unsigned short* cb = &smem[cur*8192];
    short8 af[4], bfr[4];
    #pragma unroll
    for (int mi=0;mi<4;mi++)
      af[mi] = *(const short8*)&cb[(wr*64 + mi*16 + lr)*32 + g*8];
    #pragma unroll
    for (int ni=0;ni<4;ni++)
      bfr[ni] = *(const short8*)&cb[4096 + (wc*64 + ni*16 + lr)*32 + g*8];
    #pragma unroll
    for (int mi=0;mi<4;mi++)
      #pragma unroll
      for (int ni=0;ni<4;ni++)
        acc[mi][ni] = __builtin_amdgcn_mfma_f32_16x16x32_bf16(af[mi], bfr[ni], acc[mi][ni], 0, 0, 0);

    // all reads of cb consumed (lgkm waits precede MFMA); barrier before overwrite
    __builtin_amdgcn_s_barrier();
    cur ^= 1;
  }

  #pragma unroll
  for (int mi=0;mi<4;mi++){
    const int rb = rowA0 + wr*64 + mi*16 + g*4;
    const int b  = rb >> 11, l0 = rb & 2047;
    #pragma unroll
    for (int ni=0;ni<4;ni++){
      const int col = rowB0 + wc*64 + ni*16 + lr;
      if (MODE == 0) {
        const int sec = col >> 10;
        const int nl  = col & 1023;
        const int h = nl >> 6, d = nl & 63;
        const size_t bh = (size_t)(b*NH + h);
        if (sec == 2) {
          // V^T: r=0..3 are consecutive l -> one packed 8B store
          const float bias = b2[nl];
          ushort4 s;
          s.x = f2bf(acc[mi][ni][0]+bias); s.y = f2bf(acc[mi][ni][1]+bias);
          s.z = f2bf(acc[mi][ni][2]+bias); s.w = f2bf(acc[mi][ni][3]+bias);
          *(ushort4*)&vo[(bh*HD + d)*L_SEQ + l0] = s;
        } else {
          const float bias = (sec==0) ? b0[nl] : b1[nl];
          #pragma unroll
          for (int r=0;r<4;r++){
            float v = acc[mi][ni][r] + bias;
            if (sec == 0) v *= QSCALE;           // fold hd^-0.5 * log2e into Q
            const unsigned short hv = f2bf(v);
            if (sec == 0) qo[(bh*L_SEQ + l0 + r)*HD + d] = hv;
            else          ko[(bh*L_SEQ + l0 + r)*HD + d] = hv;
          }
        }
      } else {
        const float bias = b0[col];
        #pragma unroll
        for (int r=0;r<4;r++)
          out[((size_t)(l0 + r)*BATCH + b)*CDIM + col] = acc[mi][ni][r] + bias;
      }
    }
  }
}

// ---------------- flash attention: LDS-staged K/V, counted-vmcnt pipeline ----------------
// grid: x = b*NH+h (32)  [same-bh blocks land on same XCD], y = q-block of 64.
// LDS: K tiles 2x8KB + V tiles 2x8KB + P 8KB = 40KB -> 4 blocks/CU.
__global__ void __launch_bounds__(256) attn_kernel(
    const unsigned short* __restrict__ Qb, const unsigned short* __restrict__ Kb,
    const unsigned short* __restrict__ Vt, const float* __restrict__ rel,
    unsigned short* __restrict__ Ab)
{
  __shared__ unsigned short Ks[2][64*64];
  __shared__ unsigned short Vs[2][64*64];
  __shared__ unsigned int Pl[4*16*32];   // per-wave [16 q][32 u32], XOR-swizzled
  const int bh = blockIdx.x;
  const int qb = blockIdx.y;
  const int t = threadIdx.x, lane = t & 63, wave = t >> 6;
  const int g = lane >> 4, lr = lane & 15;

  const unsigned short* Qp = Qb + (size_t)bh * (L_SEQ*HD);
  const unsigned short* Kp = Kb + (size_t)bh * (L_SEQ*HD);
  const unsigned short* Vp = Vt + (size_t)bh * (HD*L_SEQ);

  const int q0 = qb*64 + wave*16;                 // this wave's q-rows
  const short8 qf0 = *(const short8*)&Qp[(size_t)(q0 + lr)*HD + g*8];
  const short8 qf1 = *(const short8*)&Qp[(size_t)(q0 + lr)*HD + 32 + g*8];

  // rel index for key k: k - q + 2047; per-lane base
  const float* relp = rel + (2047 - q0 - lr + g*4);

  unsigned int* pw = Pl + wave*512 + lr*32;
  const int swz = lr & 7;

  // all-ones bf16 A-fragment for MFMA row-sum (layout-independent)
  const short ONE = (short)0x3F80;
  const short8 ones = { ONE,ONE,ONE,ONE,ONE,ONE,ONE,ONE };

  // staging mapping: thread t covers LDS bytes [t*16, t*16+16) (+4096 on round 2)
  const int srow = t >> 3;                 // 0..31 (round adds 32; (row+32)&7==row&7)
  const int sxor = (t & 7) ^ (srow & 7);   // pre-swizzled source unit

  const unsigned short* kg = Kp + (size_t)srow*HD + sxor*8;
  const unsigned short* vg = Vp + (size_t)srow*L_SEQ + sxor*8;

  floatx4 o[4] = {};
  floatx4 osum = {};     // MFMA-accumulated row sums (all 4 entries equal)
  float m = -1e30f;

  // prologue: stage tile 0 into buffer 0 (completion enforced in-loop)
  gload_lds16(kg,           &Ks[0][t*8]);
  gload_lds16(kg + 32*HD,   &Ks[0][2048 + t*8]);
  gload_lds16(vg,           &Vs[0][t*8]);
  gload_lds16(vg + (size_t)32*L_SEQ, &Vs[0][2048 + t*8]);

  int cur = 0;
  for (int kb = 0; kb < L_SEQ; kb += 64) {
    // stage next tile (wraps to 0 on last iter; harmless)
    {
      const int kbn = (kb + 64) & (L_SEQ - 1);
      const unsigned short* kgn = kg + (size_t)kbn*HD;   // rows kbn+srow
      const unsigned short* vgn = vg + kbn;              // cols kbn
      unsigned short* kd = &Ks[cur^1][0];
      unsigned short* vd = &Vs[cur^1][0];
      gload_lds16(kgn,                    kd + t*8);
      gload_lds16(kgn + 32*HD,            kd + 2048 + t*8);
      gload_lds16(vgn,                    vd + t*8);
      gload_lds16(vgn + (size_t)32*L_SEQ, vd + 2048 + t*8);
    }
    // counted wait: 4 newest outstanding = stage(t+1); everything older (stage(t)) done
    asm volatile("s_waitcnt vmcnt(4)" ::: "memory");
    __builtin_amdgcn_s_barrier();

    // rel loads (global, L1/L2-resident)
    float relv[16];
    #pragma unroll
    for (int j=0;j<4;j++)
      #pragma unroll
      for (int r=0;r<4;r++)
        relv[4*j+r] = relp[kb + 16*j + r];

    // QK^T from LDS: lane holds 16 keys {16j+4g+r} for q-row q0+lr
    const unsigned short* kbuf = &Ks[cur][0];
    floatx4 s[4];
    #pragma unroll
    for (int j=0;j<4;j++){
      const int row = j*16 + lr;
      const short8 k0 = *(const short8*)&kbuf[row*64 + ((g    ) ^ swz)*8];
      const short8 k1 = *(const short8*)&kbuf[row*64 + ((4 + g) ^ swz)*8];
      floatx4 z = {};
      z = __builtin_amdgcn_mfma_f32_16x16x32_bf16(k0, qf0, z, 0,0,0);
      z = __builtin_amdgcn_mfma_f32_16x16x32_bf16(k1, qf1, z, 0,0,0);
      s[j] = z;
    }

    float p[16];
    #pragma unroll
    for (int j=0;j<4;j++)
      #pragma unroll
      for (int r=0;r<4;r++)
        p[4*j+r] = fmaf(relv[4*j+r], QSCALE, s[j][r]);   // log2-domain score

    // per-lane tile max: 3-input groups to fuse into v_max3_f32
    float ma = fmaxf(fmaxf(fmaxf(p[0],p[1]),p[2]),  fmaxf(fmaxf(p[3],p[4]),p[5]));
    float mb = fmaxf(fmaxf(fmaxf(p[6],p[7]),p[8]),  fmaxf(fmaxf(p[9],p[10]),p[11]));
    float mc = fmaxf(fmaxf(fmaxf(p[12],p[13]),p[14]), p[15]);
    float mxl = fmaxf(fmaxf(ma, mb), mc);

    // T13 defer-max: rescale only when max grew by >8 (exp2(8)=256 headroom)
    if (!__all(mxl <= m + 8.f)) {
      float mx = fmaxf(mxl, __shfl_xor(mxl, 16, 64));
      mx = fmaxf(mx, __shfl_xor(mx, 32, 64));
      const float mn = fmaxf(m, mx);
      const float al = exp2f(m - mn);
      m = mn;
      #pragma unroll
      for (int r=0;r<4;r++) osum[r] *= al;
      #pragma unroll
      for (int fb=0;fb<4;fb++)
        #pragma unroll
        for (int r=0;r<4;r++) o[fb][r] *= al;
    }

    #pragma unroll
    for (int i=0;i<16;i++) p[i] = exp2f(p[i] - m);

    // P -> LDS (per-wave): 128B rows, 16B-unit swizzle; cvt_pk packs
    #pragma unroll
    for (int j=0;j<4;j++){
      unsigned lo = cvtpk(p[4*j],   p[4*j+1]);
      unsigned hi = cvtpk(p[4*j+2], p[4*j+3]);
      const int unit = (2*j + (g>>1)) ^ swz;
      *(uint2*)&pw[unit*4 + (g&1)*2] = make_uint2(lo, hi);
    }
    asm volatile("" ::: "memory");
    const short8 pf0 = *(const short8*)&pw[((    g) ^ swz)*4];
    const short8 pf1 = *(const short8*)&pw[((4 + g) ^ swz)*4];
    asm volatile("" ::: "memory");

    // row-sum on the MFMA pipe: D[i][q] = sum_k P[q,k] for every i
    osum = __builtin_amdgcn_mfma_f32_16x16x32_bf16(ones, pf0, osum, 0,0,0);
    osum = __builtin_amdgcn_mfma_f32_16x16x32_bf16(ones, pf1, osum, 0,0,0);

    // PV from LDS V^T tile
    const unsigned short* vbuf = &Vs[cur][0];
    #pragma unroll
    for (int fb=0; fb<4; fb++){
      const int row = fb*16 + lr;
      const short8 v0 = *(const short8*)&vbuf[row*64 + ((g    ) ^ swz)*8];
      const short8 v1 = *(const short8*)&vbuf[row*64 + ((4 + g) ^ swz)*8];
      o[fb] = __builtin_amdgcn_mfma_f32_16x16x32_bf16(v0, pf0, o[fb], 0,0,0);
      o[fb] = __builtin_amdgcn_mfma_f32_16x16x32_bf16(v1, pf1, o[fb], 0,0,0);
    }

    // all reads of buf[cur] consumed (compiler lgkm-waits before MFMA use);
    // barrier before next iter's stage overwrites it
    __builtin_amdgcn_s_barrier();
    cur ^= 1;
  }

  // lane (g,lr) holds attn[q=q0+lr][d = fb*16 + g*4 + r]
  const float inv = 1.f / osum[0];
  const int b = bh >> 4, h = bh & 15;
  unsigned short* outp = &Ab[((size_t)(b*L_SEQ + q0 + lr))*CDIM + h*HD];
  #pragma unroll
  for (int fb=0; fb<4; fb++){
    #pragma unroll
    for (int rp=0; rp<2; rp++){
      *(unsigned int*)&outp[fb*16 + g*4 + 2*rp] =
          cvtpk(o[fb][2*rp] * inv, o[fb][2*rp+1] * inv);
    }
  }
}

extern "C" void kernel_launch(void* const* d_in, const int* in_sizes, int n_in,
                              void* d_out, int out_size, void* d_ws, size_t ws_size,
                              hipStream_t stream) {
  const float* x   = (const float*)d_in[0];
  const float* Wq  = (const float*)d_in[1];
  const float* bq  = (const float*)d_in[2];
  const float* Wk  = (const float*)d_in[3];
  const float* bk  = (const float*)d_in[4];
  const float* Wv  = (const float*)d_in[5];
  const float* bv  = (const float*)d_in[6];
  const float* Wo  = (const float*)d_in[7];
  const float* bo  = (const float*)d_in[8];
  const float* rel = (const float*)d_in[9];
  float* out = (float*)d_out;

  char* ws = (char*)d_ws;
  unsigned short* Xb    = (unsigned short*)(ws);                    // 8 MB (aliased with Ab)
  unsigned short* Wqkvt = (unsigned short*)(ws + (8u  << 20));      // 6 MB
  unsigned short* Wot   = (unsigned short*)(ws + (14u << 20));      // 2 MB
  unsigned short* Qb    = (unsigned short*)(ws + (16u << 20));      // 8 MB
  unsigned short* Kb    = (unsigned short*)(ws + (24u << 20));      // 8 MB
  unsigned short* Vt    = (unsigned short*)(ws + (32u << 20));      // 8 MB
  unsigned short* Ab    = Xb;  // Xb dead after QKV GEMM

  prep_x<<<4096, 256, 0, stream>>>(x, Xb);
  prep_w<<<dim3(32,32,4), 256, 0, stream>>>(Wq, Wk, Wv, Wo, Wqkvt, Wot);
  gemm_bt<0><<<dim3(32,24), 256, 0, stream>>>(Xb, Wqkvt, CDIM, bq, bk, bv,
                                              Qb, Kb, Vt, nullptr);
  attn_kernel<<<dim3(32,32), 256, 0, stream>>>(Qb, Kb, Vt, rel, Ab);
  gemm_bt<1><<<dim3(32,8), 256, 0, stream>>>(Ab, Wot, CDIM, bo, nullptr, nullptr,
                                             nullptr, nullptr, nullptr, out);
}